// Round 17
// baseline (269.619 us; speedup 1.0000x reference)
//
#include <hip/hip_runtime.h>

#define NN 100000
#define NE 1200000
#define NG 8
#define DIM 64
#define SCAN_BS 256
#define NB ((NN + SCAN_BS - 1) / SCAN_BS)  // 391
#define COLCAP (NE + 7 * NN)  // ceil8 padding worst case
#define GT 128                // gemm tile nodes

// histogram partition: 13 ranges x 8192 nodes (32KB LDS), 28 edge slices
#define RANGE 8192
#define NR 13
#define GSL 28
#define SLICE4 ((NE / 4 + GSL - 1) / GSL)

// ---- range-partitioned LDS histogram ----
__global__ __launch_bounds__(256) void hist_kernel(const int4* __restrict__ esrc4,
                                                   const int4* __restrict__ edst4,
                                                   int* __restrict__ partial) {
  __shared__ int h[RANGE];
  int job = blockIdx.x;
  int g = job % GSL;
  int r = (job / GSL) % NR;
  int dir = job / (GSL * NR);
  const int4* __restrict__ idx = dir ? edst4 : esrc4;
  int lo = r * RANGE, hi = min(lo + RANGE, NN);
  for (int i = threadIdx.x; i < RANGE / 4; i += 256) ((int4*)h)[i] = make_int4(0, 0, 0, 0);
  __syncthreads();
  int s0 = g * SLICE4, s1 = min(s0 + SLICE4, NE / 4);
  for (int i = s0 + threadIdx.x; i < s1; i += 256) {
    int4 v = idx[i];
    if (v.x >= lo && v.x < hi) atomicAdd(&h[v.x - lo], 1);
    if (v.y >= lo && v.y < hi) atomicAdd(&h[v.y - lo], 1);
    if (v.z >= lo && v.z < hi) atomicAdd(&h[v.z - lo], 1);
    if (v.w >= lo && v.w < hi) atomicAdd(&h[v.w - lo], 1);
  }
  __syncthreads();
  int4* dst = (int4*)(partial + (size_t)job * RANGE);
  int cap4 = (hi - lo) >> 2;
  for (int i = threadIdx.x; i < cap4; i += 256) dst[i] = ((int4*)h)[i];
}

// ---- reduce partials -> indeg, snorm/dnorm ----
__global__ void reduce_kernel(const int* __restrict__ partial, int* __restrict__ indeg,
                              float* __restrict__ snormA, float* __restrict__ dnormA, int N) {
  int t = blockIdx.x * blockDim.x + threadIdx.x;
  if (t >= 2 * N) return;
  int dir = t >= N;
  int n = dir ? t - N : t;
  int r = n >> 13, off = n & (RANGE - 1);
  const int* p = partial + (((size_t)dir * NR + r) * GSL) * RANGE + off;
  int s = 0;
#pragma unroll
  for (int g = 0; g < GSL; ++g) s += p[(size_t)g * RANGE];
  float nv = rsqrtf(fmaxf((float)s, 1.0f));
  if (dir) { indeg[n] = s; dnormA[n] = nv; }
  else snormA[n] = nv;
}

// ---- exclusive scan of ceil8(indeg) -> rp2 ----
__global__ __launch_bounds__(SCAN_BS) void scan1_kernel(const int* __restrict__ indeg,
                                                        int* __restrict__ rp2,
                                                        int* __restrict__ bsum, int N) {
  __shared__ int t[SCAN_BS];
  int i = blockIdx.x * SCAN_BS + threadIdx.x;
  int v = (i < N) ? ((indeg[i] + 7) & ~7) : 0;
  t[threadIdx.x] = v;
  __syncthreads();
  for (int off = 1; off < SCAN_BS; off <<= 1) {
    int u = (threadIdx.x >= off) ? t[threadIdx.x - off] : 0;
    __syncthreads();
    t[threadIdx.x] += u;
    __syncthreads();
  }
  if (i < N) rp2[i] = t[threadIdx.x] - v;
  if (i == N - 1) rp2[N] = t[threadIdx.x];
  if (threadIdx.x == SCAN_BS - 1) bsum[blockIdx.x] = t[threadIdx.x];
}

__global__ __launch_bounds__(512) void scan2_kernel(const int* __restrict__ bsum,
                                                    int* __restrict__ boff, int nb) {
  __shared__ int t[512];
  int v = ((int)threadIdx.x < nb) ? bsum[threadIdx.x] : 0;
  t[threadIdx.x] = v;
  __syncthreads();
  for (int off = 1; off < 512; off <<= 1) {
    int u = (threadIdx.x >= off) ? t[threadIdx.x - off] : 0;
    __syncthreads();
    t[threadIdx.x] += u;
    __syncthreads();
  }
  boff[threadIdx.x] = t[threadIdx.x] - v;
}

__global__ __launch_bounds__(SCAN_BS) void scan3_kernel(int* __restrict__ rp2,
                                                        const int* __restrict__ boff, int N) {
  int i = blockIdx.x * SCAN_BS + threadIdx.x;
  if (i < N) rp2[i] += boff[blockIdx.x];
  if (i == N - 1) rp2[N] += boff[blockIdx.x];
}

// ---- in-place: partial[1][r][g][i] -> absolute start offset ----
__global__ void offscan_kernel(int* __restrict__ partial, const int* __restrict__ rp2, int N) {
  int n = blockIdx.x * blockDim.x + threadIdx.x;
  if (n >= N) return;
  int r = n >> 13, i = n & (RANGE - 1);
  int* p = partial + (((size_t)NR + r) * GSL) * RANGE + i;
  int running = rp2[n];
#pragma unroll
  for (int g = 0; g < GSL; ++g) {
    int tmp = p[(size_t)g * RANGE];
    p[(size_t)g * RANGE] = running;
    running += tmp;
  }
}

// ---- init col with NN (zero-row index) ----
__global__ void colinit_kernel(int4* __restrict__ col4, int n4) {
  int i = blockIdx.x * blockDim.x + threadIdx.x;
  int st = gridDim.x * blockDim.x;
  for (; i < n4; i += st) col4[i] = make_int4(NN, NN, NN, NN);
}

// ---- fill CSR col: LDS-offset slot assignment, no global atomics ----
__global__ __launch_bounds__(256) void fill_kernel(const int4* __restrict__ esrc4,
                                                   const int4* __restrict__ edst4,
                                                   const int* __restrict__ partial,
                                                   int* __restrict__ col) {
  __shared__ int cnt[RANGE];
  int job = blockIdx.x;  // NR*GSL
  int g = job % GSL, r = job / GSL;
  int lo = r * RANGE, hi = min(lo + RANGE, NN);
  const int* off = partial + (((size_t)NR + r) * GSL + g) * RANGE;
  for (int i = threadIdx.x; i < hi - lo; i += 256) cnt[i] = off[i];
  __syncthreads();
  int s0 = g * SLICE4, s1 = min(s0 + SLICE4, NE / 4);
  for (int i = s0 + threadIdx.x; i < s1; i += 256) {
    int4 d = edst4[i];
    int4 s = esrc4[i];
    if (d.x >= lo && d.x < hi) col[atomicAdd(&cnt[d.x - lo], 1)] = s.x;
    if (d.y >= lo && d.y < hi) col[atomicAdd(&cnt[d.y - lo], 1)] = s.y;
    if (d.z >= lo && d.z < hi) col[atomicAdd(&cnt[d.z - lo], 1)] = s.z;
    if (d.w >= lo && d.w < hi) col[atomicAdd(&cnt[d.w - lo], 1)] = s.w;
  }
}

// ---- dense GEMM: Z[n] = (X[n] * (SCALE? snorm[n] : 1)) @ W ; tile 128 nodes ----
// register tile 8n x 4j per thread; aT (transposed) + W in LDS.
template <int SCALE>
__global__ __launch_bounds__(256) void gemm_kernel(
    const float* __restrict__ X, const float* __restrict__ snormA,
    const float* __restrict__ W, float* __restrict__ Z, int N) {
  __shared__ float aT[DIM][GT + 1];  // [k][node], pad 129 -> conflict-free
  __shared__ float Wl[DIM][DIM + 4]; // [k][j], pad 68
  const int t = threadIdx.x;
  const int nb = blockIdx.x * GT;

  for (int i = t; i < DIM * 16; i += 256) {  // W: 1024 float4
    int k = i >> 4, c4 = (i & 15) << 2;
    *(float4*)&Wl[k][c4] = *(const float4*)(W + k * DIM + c4);
  }
#pragma unroll
  for (int r = 0; r < 8; ++r) {  // A^T stage: 2048 float4 reads
    int i = t + r * 256;
    int node = i >> 4, kc = i & 15;
    int n = nb + node;
    float4 a = make_float4(0.f, 0.f, 0.f, 0.f);
    float sc = 1.0f;
    if (n < N) {
      a = *(const float4*)(X + (size_t)n * DIM + kc * 4);
      if (SCALE) sc = snormA[n];
    }
    if (SCALE) { a.x *= sc; a.y *= sc; a.z *= sc; a.w *= sc; }
    aT[kc * 4 + 0][node] = a.x;
    aT[kc * 4 + 1][node] = a.y;
    aT[kc * 4 + 2][node] = a.z;
    aT[kc * 4 + 3][node] = a.w;
  }
  __syncthreads();

  const int n0 = (t >> 4) * 8;  // 16 node-chunks of 8 (wave covers 4 -> conflict-free reads)
  const int j0 = (t & 15) * 4;  // 16 j-chunks of 4
  float4 acc0 = {0,0,0,0}, acc1 = {0,0,0,0}, acc2 = {0,0,0,0}, acc3 = {0,0,0,0};
  float4 acc4 = {0,0,0,0}, acc5 = {0,0,0,0}, acc6 = {0,0,0,0}, acc7 = {0,0,0,0};
#pragma unroll 4
  for (int k = 0; k < DIM; ++k) {
    float4 w = *(const float4*)&Wl[k][j0];
    float4 aA = *(const float4*)&aT[k][n0];
    float4 aB = *(const float4*)&aT[k][n0 + 4];
    acc0.x = fmaf(aA.x, w.x, acc0.x); acc0.y = fmaf(aA.x, w.y, acc0.y);
    acc0.z = fmaf(aA.x, w.z, acc0.z); acc0.w = fmaf(aA.x, w.w, acc0.w);
    acc1.x = fmaf(aA.y, w.x, acc1.x); acc1.y = fmaf(aA.y, w.y, acc1.y);
    acc1.z = fmaf(aA.y, w.z, acc1.z); acc1.w = fmaf(aA.y, w.w, acc1.w);
    acc2.x = fmaf(aA.z, w.x, acc2.x); acc2.y = fmaf(aA.z, w.y, acc2.y);
    acc2.z = fmaf(aA.z, w.z, acc2.z); acc2.w = fmaf(aA.z, w.w, acc2.w);
    acc3.x = fmaf(aA.w, w.x, acc3.x); acc3.y = fmaf(aA.w, w.y, acc3.y);
    acc3.z = fmaf(aA.w, w.z, acc3.z); acc3.w = fmaf(aA.w, w.w, acc3.w);
    acc4.x = fmaf(aB.x, w.x, acc4.x); acc4.y = fmaf(aB.x, w.y, acc4.y);
    acc4.z = fmaf(aB.x, w.z, acc4.z); acc4.w = fmaf(aB.x, w.w, acc4.w);
    acc5.x = fmaf(aB.y, w.x, acc5.x); acc5.y = fmaf(aB.y, w.y, acc5.y);
    acc5.z = fmaf(aB.y, w.z, acc5.z); acc5.w = fmaf(aB.y, w.w, acc5.w);
    acc6.x = fmaf(aB.z, w.x, acc6.x); acc6.y = fmaf(aB.z, w.y, acc6.y);
    acc6.z = fmaf(aB.z, w.z, acc6.z); acc6.w = fmaf(aB.z, w.w, acc6.w);
    acc7.x = fmaf(aB.w, w.x, acc7.x); acc7.y = fmaf(aB.w, w.y, acc7.y);
    acc7.z = fmaf(aB.w, w.z, acc7.z); acc7.w = fmaf(aB.w, w.w, acc7.w);
  }
  int n = nb + n0;
#define STORE_Z(m, accm) if (n + m < N) *(float4*)(Z + (size_t)(n + m) * DIM + j0) = accm;
  STORE_Z(0, acc0) STORE_Z(1, acc1) STORE_Z(2, acc2) STORE_Z(3, acc3)
  STORE_Z(4, acc4) STORE_Z(5, acc5) STORE_Z(6, acc6) STORE_Z(7, acc7)
#undef STORE_Z
}

// ---- gather + elementwise epilogue: acc = sum z[col]; r = relu(dn*acc + b) ----
// POOL=0: y[n] = r * snorm[n]   POOL=1: per-graph pooling (no store)
template <int POOL>
__global__ __launch_bounds__(256, 8) void gather_kernel(
    const float* __restrict__ xs, const float* __restrict__ dnormA,
    const float* __restrict__ bias, const float* __restrict__ snormA,
    const int* __restrict__ rp2, const int* __restrict__ col,
    float* __restrict__ y, const int* __restrict__ gid,
    float* __restrict__ gsum, float* __restrict__ gcnt, int N) {
  __shared__ float lsum[NG * DIM];
  __shared__ float lcnt[NG];
  if (POOL) {
    for (int i = threadIdx.x; i < NG * DIM; i += 256) lsum[i] = 0.0f;
    if (threadIdx.x < NG) lcnt[threadIdx.x] = 0.0f;
    __syncthreads();
  }
  const int lane = threadIdx.x & 63;
  const int wid = threadIdx.x >> 6;
  const int g = lane >> 4;
  const int idx = lane & 15;
  const int t4 = idx << 2;
  const float4 bb = *(const float4*)(bias + t4);
  const int waveId = blockIdx.x * 4 + wid;
  const int stride4 = gridDim.x * 16;

  for (int n4 = waveId * 4; n4 < N; n4 += stride4) {
    int n = n4 + g;
    bool valid = n < N;
    int nc = valid ? n : 0;
    int base = rp2[nc];
    int end = rp2[nc + 1];
    float4 acc = make_float4(0.f, 0.f, 0.f, 0.f);
    float4 acc2 = make_float4(0.f, 0.f, 0.f, 0.f);
    for (int p = base; p < end; p += 8) {
      int4 c0 = *(const int4*)(col + p);
      int4 c1 = *(const int4*)(col + p + 4);
      float4 v0 = *(const float4*)(xs + (size_t)c0.x * DIM + t4);
      float4 v1 = *(const float4*)(xs + (size_t)c0.y * DIM + t4);
      float4 v2 = *(const float4*)(xs + (size_t)c0.z * DIM + t4);
      float4 v3 = *(const float4*)(xs + (size_t)c0.w * DIM + t4);
      float4 v4 = *(const float4*)(xs + (size_t)c1.x * DIM + t4);
      float4 v5 = *(const float4*)(xs + (size_t)c1.y * DIM + t4);
      float4 v6 = *(const float4*)(xs + (size_t)c1.z * DIM + t4);
      float4 v7 = *(const float4*)(xs + (size_t)c1.w * DIM + t4);
      acc.x += (v0.x + v1.x) + (v2.x + v3.x);
      acc.y += (v0.y + v1.y) + (v2.y + v3.y);
      acc.z += (v0.z + v1.z) + (v2.z + v3.z);
      acc.w += (v0.w + v1.w) + (v2.w + v3.w);
      acc2.x += (v4.x + v5.x) + (v6.x + v7.x);
      acc2.y += (v4.y + v5.y) + (v6.y + v7.y);
      acc2.z += (v4.z + v5.z) + (v6.z + v7.z);
      acc2.w += (v4.w + v5.w) + (v6.w + v7.w);
    }
    if (valid) {
      float dn = dnormA[n];
      float4 r;
      r.x = fmaxf(fmaf(dn, acc.x + acc2.x, bb.x), 0.f);
      r.y = fmaxf(fmaf(dn, acc.y + acc2.y, bb.y), 0.f);
      r.z = fmaxf(fmaf(dn, acc.z + acc2.z, bb.z), 0.f);
      r.w = fmaxf(fmaf(dn, acc.w + acc2.w, bb.w), 0.f);
      if (POOL) {
        int gi = gid[n];
        atomicAdd(&lsum[gi * DIM + t4 + 0], r.x);
        atomicAdd(&lsum[gi * DIM + t4 + 1], r.y);
        atomicAdd(&lsum[gi * DIM + t4 + 2], r.z);
        atomicAdd(&lsum[gi * DIM + t4 + 3], r.w);
        if (idx == 0) atomicAdd(&lcnt[gi], 1.0f);
      } else {
        float sn = snormA[n];  // prescale for next layer
        r.x *= sn; r.y *= sn; r.z *= sn; r.w *= sn;
        *(float4*)(y + (size_t)n * DIM + t4) = r;
      }
    }
  }

  if (POOL) {
    __syncthreads();
    for (int i = threadIdx.x; i < NG * DIM; i += 256) atomicAdd(&gsum[i], lsum[i]);
    if (threadIdx.x < NG) atomicAdd(&gcnt[threadIdx.x], lcnt[threadIdx.x]);
  }
}

// ---- head ----
__global__ void final_kernel(const float* __restrict__ gsum, const float* __restrict__ gcnt,
                             const float* __restrict__ Wp, const float* __restrict__ bp,
                             float* __restrict__ out) {
  int lane = threadIdx.x;  // 64
#pragma unroll
  for (int g = 0; g < NG; ++g) {
    float inv = 1.0f / fmaxf(gcnt[g], 1.0f);
    float hv = gsum[g * DIM + lane] * inv;
#pragma unroll
    for (int c = 0; c < 2; ++c) {
      float p = hv * Wp[lane * 2 + c];
      for (int off = 32; off; off >>= 1) p += __shfl_down(p, off, 64);
      if (lane == 0) out[g * 2 + c] = p + bp[c];
    }
  }
}

extern "C" void kernel_launch(void* const* d_in, const int* in_sizes, int n_in,
                              void* d_out, int out_size, void* d_ws, size_t ws_size,
                              hipStream_t stream) {
  const float* features = (const float*)d_in[0];
  const float* W1 = (const float*)d_in[1];
  const float* b1 = (const float*)d_in[2];
  const float* W2 = (const float*)d_in[3];
  const float* b2 = (const float*)d_in[4];
  const float* Wp = (const float*)d_in[5];
  const float* bp = (const float*)d_in[6];
  const int* esrc = (const int*)d_in[7];
  const int* edst = (const int*)d_in[8];
  const int* gid = (const int*)d_in[9];
  float* out = (float*)d_out;

  const int N = NN;

  float* base = (float*)d_ws;
  size_t off = 0;
  auto alloc = [&](size_t nwords) { size_t r = off; off = (off + nwords + 15) & ~(size_t)15; return r; };

  float* gsum = base + alloc(NG * DIM);   // zeroed
  float* gcnt = base + alloc(NG);         // zeroed
  size_t zeroWords = off;
  int* indeg  = (int*)(base + alloc(N));
  float* snormA = base + alloc(N);
  float* dnormA = base + alloc(N);
  int* rp2   = (int*)(base + alloc(N + 1));
  int* bsum  = (int*)(base + alloc(512));
  int* boff  = (int*)(base + alloc(512));
  int* col   = (int*)(base + alloc(COLCAP));
  float* xs  = base + alloc((size_t)(N + 1) * DIM);  // z1 / z2 (row N = zero); partial aliases
  float* B   = base + alloc((size_t)(N + 1) * DIM);  // h1 * snorm
  int* partial = (int*)xs;  // 5,963,776 ints < 6.4M words

  hipMemsetAsync(d_ws, 0, zeroWords * sizeof(float), stream);
  hipMemsetAsync(xs + (size_t)N * DIM, 0, DIM * sizeof(float), stream);

  hist_kernel<<<2 * NR * GSL, 256, 0, stream>>>((const int4*)esrc, (const int4*)edst, partial);
  reduce_kernel<<<(2 * N + 255) / 256, 256, 0, stream>>>(partial, indeg, snormA, dnormA, N);

  scan1_kernel<<<NB, SCAN_BS, 0, stream>>>(indeg, rp2, bsum, N);
  scan2_kernel<<<1, 512, 0, stream>>>(bsum, boff, NB);
  scan3_kernel<<<NB, SCAN_BS, 0, stream>>>(rp2, boff, N);

  offscan_kernel<<<(NR * RANGE + 255) / 256, 256, 0, stream>>>(partial, rp2, N);
  colinit_kernel<<<(COLCAP / 4 + 255) / 256, 256, 0, stream>>>((int4*)col, COLCAP / 4);
  fill_kernel<<<NR * GSL, 256, 0, stream>>>((const int4*)esrc, (const int4*)edst, partial, col);

  const int GB = (N + GT - 1) / GT;  // 782 gemm tiles
  // layer 1: z1 = (x * snorm) @ W1  -> xs ; B = relu(dn*gather(z1)+b1)*snorm
  gemm_kernel<1><<<GB, 256, 0, stream>>>(features, snormA, W1, xs, N);
  gather_kernel<0><<<2048, 256, 0, stream>>>(xs, dnormA, b1, snormA, rp2, col,
                                             B, gid, gsum, gcnt, N);
  // layer 2: z2 = B @ W2 -> xs ; pool(relu(dn*gather(z2)+b2))
  gemm_kernel<0><<<GB, 256, 0, stream>>>(B, snormA, W2, xs, N);
  gather_kernel<1><<<2048, 256, 0, stream>>>(xs, dnormA, b2, snormA, rp2, col,
                                             nullptr, gid, gsum, gcnt, N);

  final_kernel<<<1, 64, 0, stream>>>(gsum, gcnt, Wp, bp, out);
}

// Round 18
// 246.302 us; speedup vs baseline: 1.0947x; 1.0947x over previous
//
#include <hip/hip_runtime.h>

#define NN 100000
#define NE 1200000
#define NG 8
#define DIM 64
#define WROW 64  // W reads are group-broadcast; 2-way bank aliasing is free
#define SCAN_BS 256
#define NB ((NN + SCAN_BS - 1) / SCAN_BS)  // 391
#define COLCAP (NE + 7 * NN)  // ceil8 padding worst case

// histogram partition: 7 ranges x 16384 nodes (64KB LDS), 28 edge slices
#define RANGE 16384
#define RSH 14
#define NR 7
#define GSL 28
#define SLICE4 ((NE / 4 + GSL - 1) / GSL)  // 10715

// ---- range-partitioned LDS histogram ----
__global__ __launch_bounds__(256) void hist_kernel(const int4* __restrict__ esrc4,
                                                   const int4* __restrict__ edst4,
                                                   int* __restrict__ partial) {
  __shared__ int h[RANGE];
  int job = blockIdx.x;
  int g = job % GSL;
  int r = (job / GSL) % NR;
  int dir = job / (GSL * NR);
  const int4* __restrict__ idx = dir ? edst4 : esrc4;
  int lo = r * RANGE, hi = min(lo + RANGE, NN);
  for (int i = threadIdx.x; i < RANGE / 4; i += 256) ((int4*)h)[i] = make_int4(0, 0, 0, 0);
  __syncthreads();
  int s0 = g * SLICE4, s1 = min(s0 + SLICE4, NE / 4);
  for (int i = s0 + threadIdx.x; i < s1; i += 256) {
    int4 v = idx[i];
    if (v.x >= lo && v.x < hi) atomicAdd(&h[v.x - lo], 1);
    if (v.y >= lo && v.y < hi) atomicAdd(&h[v.y - lo], 1);
    if (v.z >= lo && v.z < hi) atomicAdd(&h[v.z - lo], 1);
    if (v.w >= lo && v.w < hi) atomicAdd(&h[v.w - lo], 1);
  }
  __syncthreads();
  int4* dst = (int4*)(partial + (size_t)job * RANGE);
  int cap4 = (hi - lo) >> 2;  // 4096 or 424
  for (int i = threadIdx.x; i < cap4; i += 256) dst[i] = ((int4*)h)[i];
}

// ---- reduce partials -> indeg, snorm/dnorm ----
__global__ void reduce_kernel(const int* __restrict__ partial, int* __restrict__ indeg,
                              float* __restrict__ snormA, float* __restrict__ dnormA, int N) {
  int t = blockIdx.x * blockDim.x + threadIdx.x;
  if (t >= 2 * N) return;
  int dir = t >= N;
  int n = dir ? t - N : t;
  int r = n >> RSH, off = n & (RANGE - 1);
  const int* p = partial + (((size_t)dir * NR + r) * GSL) * RANGE + off;
  int s = 0;
#pragma unroll
  for (int g = 0; g < GSL; ++g) s += p[(size_t)g * RANGE];
  float nv = rsqrtf(fmaxf((float)s, 1.0f));
  if (dir) { indeg[n] = s; dnormA[n] = nv; }
  else snormA[n] = nv;
}

// ---- exclusive scan of ceil8(indeg) -> rp2 ----
__global__ __launch_bounds__(SCAN_BS) void scan1_kernel(const int* __restrict__ indeg,
                                                        int* __restrict__ rp2,
                                                        int* __restrict__ bsum, int N) {
  __shared__ int t[SCAN_BS];
  int i = blockIdx.x * SCAN_BS + threadIdx.x;
  int v = (i < N) ? ((indeg[i] + 7) & ~7) : 0;
  t[threadIdx.x] = v;
  __syncthreads();
  for (int off = 1; off < SCAN_BS; off <<= 1) {
    int u = (threadIdx.x >= off) ? t[threadIdx.x - off] : 0;
    __syncthreads();
    t[threadIdx.x] += u;
    __syncthreads();
  }
  if (i < N) rp2[i] = t[threadIdx.x] - v;
  if (i == N - 1) rp2[N] = t[threadIdx.x];
  if (threadIdx.x == SCAN_BS - 1) bsum[blockIdx.x] = t[threadIdx.x];
}

__global__ __launch_bounds__(512) void scan2_kernel(const int* __restrict__ bsum,
                                                    int* __restrict__ boff, int nb) {
  __shared__ int t[512];
  int v = ((int)threadIdx.x < nb) ? bsum[threadIdx.x] : 0;
  t[threadIdx.x] = v;
  __syncthreads();
  for (int off = 1; off < 512; off <<= 1) {
    int u = (threadIdx.x >= off) ? t[threadIdx.x - off] : 0;
    __syncthreads();
    t[threadIdx.x] += u;
    __syncthreads();
  }
  boff[threadIdx.x] = t[threadIdx.x] - v;
}

__global__ __launch_bounds__(SCAN_BS) void scan3_kernel(int* __restrict__ rp2,
                                                        const int* __restrict__ boff, int N) {
  int i = blockIdx.x * SCAN_BS + threadIdx.x;
  if (i < N) rp2[i] += boff[blockIdx.x];
  if (i == N - 1) rp2[N] += boff[blockIdx.x];
}

// ---- in-place: partial[1][r][g][i] -> absolute start offset ----
__global__ void offscan_kernel(int* __restrict__ partial, const int* __restrict__ rp2, int N) {
  int n = blockIdx.x * blockDim.x + threadIdx.x;
  if (n >= N) return;
  int r = n >> RSH, i = n & (RANGE - 1);
  int* p = partial + (((size_t)NR + r) * GSL) * RANGE + i;
  int running = rp2[n];
#pragma unroll
  for (int g = 0; g < GSL; ++g) {
    int tmp = p[(size_t)g * RANGE];
    p[(size_t)g * RANGE] = running;
    running += tmp;
  }
}

// ---- init col with NN (zero-row index) ----
__global__ void colinit_kernel(int4* __restrict__ col4, int n4) {
  int i = blockIdx.x * blockDim.x + threadIdx.x;
  int st = gridDim.x * blockDim.x;
  for (; i < n4; i += st) col4[i] = make_int4(NN, NN, NN, NN);
}

// ---- fill CSR col: LDS-offset slot assignment, no global atomics ----
__global__ __launch_bounds__(256) void fill_kernel(const int4* __restrict__ esrc4,
                                                   const int4* __restrict__ edst4,
                                                   const int* __restrict__ partial,
                                                   int* __restrict__ col) {
  __shared__ int cnt[RANGE];
  int job = blockIdx.x;  // NR*GSL
  int g = job % GSL, r = job / GSL;
  int lo = r * RANGE, hi = min(lo + RANGE, NN);
  const int* off = partial + (((size_t)NR + r) * GSL + g) * RANGE;
  for (int i = threadIdx.x; i < hi - lo; i += 256) cnt[i] = off[i];
  __syncthreads();
  int s0 = g * SLICE4, s1 = min(s0 + SLICE4, NE / 4);
  for (int i = s0 + threadIdx.x; i < s1; i += 256) {
    int4 d = edst4[i];
    int4 s = esrc4[i];
    if (d.x >= lo && d.x < hi) col[atomicAdd(&cnt[d.x - lo], 1)] = s.x;
    if (d.y >= lo && d.y < hi) col[atomicAdd(&cnt[d.y - lo], 1)] = s.y;
    if (d.z >= lo && d.z < hi) col[atomicAdd(&cnt[d.z - lo], 1)] = s.z;
    if (d.w >= lo && d.w < hi) col[atomicAdd(&cnt[d.w - lo], 1)] = s.w;
  }
}

// ---- xs = features * snorm ----
__global__ void prescale_kernel(const float* __restrict__ f, const float* __restrict__ snormA,
                                float* __restrict__ xs, int N) {
  int i = blockIdx.x * blockDim.x + threadIdx.x;
  if (i < N * 16) {
    int n = i >> 4;
    float sn = snormA[n];
    float4 v = ((const float4*)f)[i];
    v.x *= sn; v.y *= sn; v.z *= sn; v.w *= sn;
    ((float4*)xs)[i] = v;
  }
}

// ---- fused gather + dnorm + MLP(relu); 4 nodes/wave; LDS a-staging epilogue ----
// POOL=0: out[n] = (relu(...)@W+b) * snorm (prescale for next layer)
// POOL=1: fused per-graph pooling, no node output
template <int POOL>
__global__ __launch_bounds__(256) void gconv_kernel(
    const float* __restrict__ xs, const float* __restrict__ snormA, const float* __restrict__ dnormA,
    const int* __restrict__ rp2, const int* __restrict__ col,
    const float* __restrict__ W, const float* __restrict__ b,
    float* __restrict__ out, const int* __restrict__ gid,
    float* __restrict__ gsum, float* __restrict__ gcnt, int N) {
  __shared__ float Wt[DIM * WROW];   // W row-major (group-broadcast reads)
  __shared__ float aL[4][4][DIM];    // [wave][group][dim] wave-private a-staging
  __shared__ float lsum[NG * DIM];
  __shared__ float lcnt[NG];
  for (int i = threadIdx.x; i < DIM * 16; i += 256) {
    int k = i >> 4, ch = i & 15;
    *(float4*)&Wt[k * WROW + ch * 4] = *(const float4*)(W + k * DIM + ch * 4);
  }
  if (POOL) {
    for (int i = threadIdx.x; i < NG * DIM; i += 256) lsum[i] = 0.0f;
    if (threadIdx.x < NG) lcnt[threadIdx.x] = 0.0f;
  }
  __syncthreads();

  const int lane = threadIdx.x & 63;
  const int wid = threadIdx.x >> 6;
  const int g = lane >> 4;   // which node of the 4
  const int idx = lane & 15; // lane within group
  const int t4 = idx << 2;   // dim chunk
  const float4 bb = *(const float4*)(b + t4);
  const int waveId = blockIdx.x * 4 + wid;
  const int stride4 = gridDim.x * 16;

  for (int n4 = waveId * 4; n4 < N; n4 += stride4) {
    int n = n4 + g;
    bool valid = n < N;
    int nc = valid ? n : 0;
    int base = rp2[nc];
    int end = rp2[nc + 1];
    float4 acc = make_float4(0.f, 0.f, 0.f, 0.f);
    float4 acc2 = make_float4(0.f, 0.f, 0.f, 0.f);
    for (int p = base; p < end; p += 8) {
      int4 c0 = *(const int4*)(col + p);
      int4 c1 = *(const int4*)(col + p + 4);
      float4 v0 = *(const float4*)(xs + (size_t)c0.x * DIM + t4);
      float4 v1 = *(const float4*)(xs + (size_t)c0.y * DIM + t4);
      float4 v2 = *(const float4*)(xs + (size_t)c0.z * DIM + t4);
      float4 v3 = *(const float4*)(xs + (size_t)c0.w * DIM + t4);
      float4 v4 = *(const float4*)(xs + (size_t)c1.x * DIM + t4);
      float4 v5 = *(const float4*)(xs + (size_t)c1.y * DIM + t4);
      float4 v6 = *(const float4*)(xs + (size_t)c1.z * DIM + t4);
      float4 v7 = *(const float4*)(xs + (size_t)c1.w * DIM + t4);
      acc.x += (v0.x + v1.x) + (v2.x + v3.x);
      acc.y += (v0.y + v1.y) + (v2.y + v3.y);
      acc.z += (v0.z + v1.z) + (v2.z + v3.z);
      acc.w += (v0.w + v1.w) + (v2.w + v3.w);
      acc2.x += (v4.x + v5.x) + (v6.x + v7.x);
      acc2.y += (v4.y + v5.y) + (v6.y + v7.y);
      acc2.z += (v4.z + v5.z) + (v6.z + v7.z);
      acc2.w += (v4.w + v5.w) + (v6.w + v7.w);
    }
    float dn = dnormA[nc];
    acc.x = (acc.x + acc2.x) * dn;
    acc.y = (acc.y + acc2.y) * dn;
    acc.z = (acc.z + acc2.z) * dn;
    acc.w = (acc.w + acc2.w) * dn;

    // stage a into wave-private LDS (no barrier: same-wave producer/consumer)
    *(float4*)&aL[wid][g][t4] = acc;

    // MLP: lane owns out dims t4..t4+3 of its group's node.
    // a[4kc..4kc+3] read as one b128 at group-uniform address (LDS broadcast).
    float4 r = bb;
#pragma unroll
    for (int kc = 0; kc < 16; ++kc) {
      float4 av = *(const float4*)&aL[wid][g][4 * kc];
      float4 w0 = *(const float4*)(Wt + (4 * kc + 0) * WROW + t4);
      float4 w1 = *(const float4*)(Wt + (4 * kc + 1) * WROW + t4);
      float4 w2 = *(const float4*)(Wt + (4 * kc + 2) * WROW + t4);
      float4 w3 = *(const float4*)(Wt + (4 * kc + 3) * WROW + t4);
      r.x = fmaf(av.x, w0.x, r.x); r.y = fmaf(av.x, w0.y, r.y);
      r.z = fmaf(av.x, w0.z, r.z); r.w = fmaf(av.x, w0.w, r.w);
      r.x = fmaf(av.y, w1.x, r.x); r.y = fmaf(av.y, w1.y, r.y);
      r.z = fmaf(av.y, w1.z, r.z); r.w = fmaf(av.y, w1.w, r.w);
      r.x = fmaf(av.z, w2.x, r.x); r.y = fmaf(av.z, w2.y, r.y);
      r.z = fmaf(av.z, w2.z, r.z); r.w = fmaf(av.z, w2.w, r.w);
      r.x = fmaf(av.w, w3.x, r.x); r.y = fmaf(av.w, w3.y, r.y);
      r.z = fmaf(av.w, w3.z, r.z); r.w = fmaf(av.w, w3.w, r.w);
    }
    r.x = fmaxf(r.x, 0.f); r.y = fmaxf(r.y, 0.f);
    r.z = fmaxf(r.z, 0.f); r.w = fmaxf(r.w, 0.f);

    if (POOL) {
      if (valid) {
        int gi = gid[n];
        atomicAdd(&lsum[gi * DIM + t4 + 0], r.x);
        atomicAdd(&lsum[gi * DIM + t4 + 1], r.y);
        atomicAdd(&lsum[gi * DIM + t4 + 2], r.z);
        atomicAdd(&lsum[gi * DIM + t4 + 3], r.w);
        if (idx == 0) atomicAdd(&lcnt[gi], 1.0f);
      }
    } else if (valid) {
      float sn = snormA[n];  // prescale for next layer's gather
      float4 o = make_float4(r.x * sn, r.y * sn, r.z * sn, r.w * sn);
      *(float4*)(out + (size_t)n * DIM + t4) = o;
    }
  }

  if (POOL) {
    __syncthreads();
    for (int i = threadIdx.x; i < NG * DIM; i += 256) atomicAdd(&gsum[i], lsum[i]);
    if (threadIdx.x < NG) atomicAdd(&gcnt[threadIdx.x], lcnt[threadIdx.x]);
  }
}

// ---- head ----
__global__ void final_kernel(const float* __restrict__ gsum, const float* __restrict__ gcnt,
                             const float* __restrict__ Wp, const float* __restrict__ bp,
                             float* __restrict__ out) {
  int lane = threadIdx.x;  // 64
#pragma unroll
  for (int g = 0; g < NG; ++g) {
    float inv = 1.0f / fmaxf(gcnt[g], 1.0f);
    float hv = gsum[g * DIM + lane] * inv;
#pragma unroll
    for (int c = 0; c < 2; ++c) {
      float p = hv * Wp[lane * 2 + c];
      for (int off = 32; off; off >>= 1) p += __shfl_down(p, off, 64);
      if (lane == 0) out[g * 2 + c] = p + bp[c];
    }
  }
}

extern "C" void kernel_launch(void* const* d_in, const int* in_sizes, int n_in,
                              void* d_out, int out_size, void* d_ws, size_t ws_size,
                              hipStream_t stream) {
  const float* features = (const float*)d_in[0];
  const float* W1 = (const float*)d_in[1];
  const float* b1 = (const float*)d_in[2];
  const float* W2 = (const float*)d_in[3];
  const float* b2 = (const float*)d_in[4];
  const float* Wp = (const float*)d_in[5];
  const float* bp = (const float*)d_in[6];
  const int* esrc = (const int*)d_in[7];
  const int* edst = (const int*)d_in[8];
  const int* gid = (const int*)d_in[9];
  float* out = (float*)d_out;

  const int N = NN;

  float* base = (float*)d_ws;
  size_t off = 0;
  auto alloc = [&](size_t nwords) { size_t r = off; off = (off + nwords + 15) & ~(size_t)15; return r; };

  float* gsum = base + alloc(NG * DIM);   // zeroed
  float* gcnt = base + alloc(NG);         // zeroed
  size_t zeroWords = off;
  int* indeg  = (int*)(base + alloc(N));
  float* snormA = base + alloc(N);
  float* dnormA = base + alloc(N);
  int* rp2   = (int*)(base + alloc(N + 1));
  int* bsum  = (int*)(base + alloc(512));
  int* boff  = (int*)(base + alloc(512));
  int* col   = (int*)(base + alloc(COLCAP));
  float* xs  = base + alloc((size_t)(N + 1) * DIM);  // partial aliases here (25.7MB < 25.9MB)
  float* B   = base + alloc((size_t)(N + 1) * DIM);
  int* partial = (int*)xs;  // 2*NR*GSL*RANGE = 6,422,528 ints = 25.69 MB (overlaps xs row N!)

  hipMemsetAsync(d_ws, 0, zeroWords * sizeof(float), stream);
  hipMemsetAsync(B + (size_t)N * DIM, 0, DIM * sizeof(float), stream);

  hist_kernel<<<2 * NR * GSL, 256, 0, stream>>>((const int4*)esrc, (const int4*)edst, partial);
  reduce_kernel<<<(2 * N + 255) / 256, 256, 0, stream>>>(partial, indeg, snormA, dnormA, N);

  scan1_kernel<<<NB, SCAN_BS, 0, stream>>>(indeg, rp2, bsum, N);
  scan2_kernel<<<1, 512, 0, stream>>>(bsum, boff, NB);
  scan3_kernel<<<NB, SCAN_BS, 0, stream>>>(rp2, boff, N);

  offscan_kernel<<<(NR * RANGE + 255) / 256, 256, 0, stream>>>(partial, rp2, N);
  colinit_kernel<<<(COLCAP / 4 + 255) / 256, 256, 0, stream>>>((int4*)col, COLCAP / 4);
  fill_kernel<<<NR * GSL, 256, 0, stream>>>((const int4*)esrc, (const int4*)edst, partial, col);

  // partial is dead now; reclaim xs: zero row N, then write prescaled features
  hipMemsetAsync(xs + (size_t)N * DIM, 0, DIM * sizeof(float), stream);
  prescale_kernel<<<(N * 16 + 255) / 256, 256, 0, stream>>>(features, snormA, xs, N);

  // layer 1: xs -> B = relu(gather(xs)*dnorm @ W1 + b1) * snorm
  gconv_kernel<0><<<2048, 256, 0, stream>>>(xs, snormA, dnormA, rp2, col, W1, b1,
                                            B, gid, gsum, gcnt, N);
  // layer 2: B -> pooled gsum/gcnt (h2 never materialized)
  gconv_kernel<1><<<2048, 256, 0, stream>>>(B, snormA, dnormA, rp2, col, W2, b2,
                                            nullptr, gid, gsum, gcnt, N);

  final_kernel<<<1, 64, 0, stream>>>(gsum, gcnt, Wp, bp, out);
}